// Round 9
// baseline (388.227 us; speedup 1.0000x reference)
//
#include <hip/hip_runtime.h>
#include <cstddef>

#define NN 50000
#define NE 400000
#define NH 4
#define NC 121
#define MAXSLOT 800000   // NE + 8*NN upper bound on 8-padded CSR slots

typedef __attribute__((ext_vector_type(8))) short short8;
typedef __attribute__((ext_vector_type(4))) float f32x4;
typedef __attribute__((ext_vector_type(2))) float f32x2;

// fp32 -> bf16 round-to-nearest-even
static __device__ __forceinline__ unsigned short f2bf(float f) {
    unsigned u = __float_as_uint(f);
    u += 0x7fffu + ((u >> 16) & 1u);
    return (unsigned short)(u >> 16);
}
// dword holding 2 bf16 -> 2 floats
static __device__ __forceinline__ f32x2 bfpair(unsigned u) {
    f32x2 r;
    r.x = __uint_as_float(u << 16);
    r.y = __uint_as_float(u & 0xffff0000u);
    return r;
}
// async global->LDS, 16B per lane; LDS dest = wave-uniform base + lane*16
static __device__ __forceinline__ void load_lds16(const unsigned short* g, unsigned short* l) {
    __builtin_amdgcn_global_load_lds(
        (const __attribute__((address_space(1))) unsigned*)g,
        (__attribute__((address_space(3))) unsigned*)l, 16, 0, 0);
}

// == fused prep: cast_x + BT1 + BT2 + BTcat + wvec3 + sentinel + dst histogram ======
#define PREP_X    3200000            // NN*256/4 float4->ushort4 items
#define PREP_BT1  (PREP_X + 65536)
#define PREP_BT2  (PREP_BT1 + 65536)
#define PREP_CAT  (PREP_BT2 + 131072)
#define PREP_WV   (PREP_CAT + 2048)
#define PREP_SENT (PREP_WV + 256)
#define PREP_END  (PREP_SENT + NE)
__global__ __launch_bounds__(256) void prep_k(const float* __restrict__ h,
                                              const float* __restrict__ W1,
                                              const float* __restrict__ W2,
                                              const float* __restrict__ W3,
                                              const float* __restrict__ al3,
                                              const float* __restrict__ ar3,
                                              const int* __restrict__ dst,
                                              unsigned short* __restrict__ h_bf,
                                              unsigned short* __restrict__ BT1,
                                              unsigned short* __restrict__ BT2,
                                              unsigned short* __restrict__ BTcat,
                                              float* __restrict__ wl3,
                                              float* __restrict__ wr3,
                                              unsigned short* __restrict__ feat_bf,
                                              float* __restrict__ el,
                                              int* __restrict__ deg) {
    int i = blockIdx.x * blockDim.x + threadIdx.x;
    if (i < PREP_X) {
        float4 v = *(const float4*)&h[(size_t)i * 4];
        ushort4 o;
        o.x = f2bf(v.x); o.y = f2bf(v.y); o.z = f2bf(v.z); o.w = f2bf(v.w);
        *(ushort4*)&h_bf[(size_t)i * 4] = o;
    } else if (i < PREP_BT1) {
        int j = i - PREP_X;
        int n = j >> 8, k = j & 255;
        BT1[j] = f2bf(W1[(size_t)k * 256 + n]);
    } else if (i < PREP_BT2) {
        int j = i - PREP_BT1;
        int n = j >> 8, k = j & 255;
        BT2[j] = f2bf(W2[(size_t)k * 256 + n]);
    } else if (i < PREP_CAT) {
        // BTcat[c][kk]: c = class (121, pad to 128 rows), kk = h*256 + k (K=1024)
        // value = 0.25 * W3[k, h*121 + c]  (0.25 = mean over heads, folded in)
        int j = i - PREP_BT2;
        int c = j >> 10, kk = j & 1023;
        int hh = kk >> 8, k = kk & 255;
        float v = (c < NC) ? 0.25f * W3[(size_t)k * 484 + hh * NC + c] : 0.f;
        BTcat[j] = f2bf(v);
    } else if (i < PREP_WV) {
        int j = (i - PREP_CAT) & 1023;
        int sel = (i - PREP_CAT) >> 10;
        int hh = j >> 8, k = j & 255;
        const float* a = sel ? ar3 : al3;
        const float* wrow = W3 + (size_t)k * 484 + hh * NC;
        const float* arow = a + hh * NC;
        float s = 0.f;
        for (int d = 0; d < NC; ++d) s += wrow[d] * arow[d];
        if (sel) wr3[j] = s; else wl3[j] = s;
    } else if (i < PREP_SENT) {
        // sentinel row NN: feat_bf[NN][*] = 0 (pad gathers read zeros);
        // el[NN][h] = -1e30 (pad logits -> exp = 0, no masking needed in agg256)
        int j = i - PREP_WV;
        feat_bf[(size_t)NN * 256 + j] = 0;
        if (j < 4) el[NN * 4 + j] = -1e30f;
    } else if (i < PREP_END) {
        atomicAdd(&deg[dst[i - PREP_SENT]], 1);
    }
}

// ====== 8-wave 128x256 MFMA GEMM for layers 1/2 (N=256, K=256): A read ONCE ======
// Wave w computes 64x64 quadrant (wm=(w>>2)*64, wn=(w&3)*64). Fused logit epilogue:
// wave's 64 output cols = one head (head = w&3).
__global__ __launch_bounds__(512) void gemm256(const unsigned short* __restrict__ A,
                                               const unsigned short* __restrict__ BT,
                                               unsigned short* __restrict__ Cb,
                                               const float* __restrict__ al,
                                               const float* __restrict__ ar,
                                               float* __restrict__ el,
                                               float* __restrict__ er,
                                               int M) {
    const int K = 256;
    __shared__ __align__(16) unsigned short Alds[128 * 32];
    __shared__ __align__(16) unsigned short Blds[256 * 32];
    const int tid = threadIdx.x;
    const int wave = tid >> 6;
    const int lane = tid & 63;
    const int quad = lane >> 4;
    const int ml = lane & 15;
    const int m0 = blockIdx.x * 128;
    const int wm0 = (wave >> 2) * 64;
    const int wn0 = (wave & 3) * 64;

    const unsigned short* Ab = A + (size_t)(m0 + wave * 16 + (lane >> 2)) * K + (lane & 3) * 8;
    const unsigned short* Bb = BT + (size_t)(wave * 16 + (lane >> 2)) * K + (lane & 3) * 8;
    unsigned short* AldsW = Alds + wave * 512;
    unsigned short* BldsW = Blds + wave * 512;

    f32x4 acc[4][4] = {};

    for (int k0 = 0; k0 < K; k0 += 32) {
        load_lds16(Ab + k0, AldsW);
        #pragma unroll
        for (int p = 0; p < 2; ++p)
            load_lds16(Bb + (size_t)(p * 128) * K + k0, BldsW + p * 4096);
        __syncthreads();

        short8 af[4], bf[4];
        #pragma unroll
        for (int i = 0; i < 4; ++i)
            af[i] = *(const short8*)&Alds[(wm0 + i * 16 + ml) * 32 + quad * 8];
        #pragma unroll
        for (int j = 0; j < 4; ++j)
            bf[j] = *(const short8*)&Blds[(wn0 + j * 16 + ml) * 32 + quad * 8];
        #pragma unroll
        for (int i = 0; i < 4; ++i)
            #pragma unroll
            for (int j = 0; j < 4; ++j)
                acc[i][j] = __builtin_amdgcn_mfma_f32_16x16x32_bf16(af[i], bf[j], acc[i][j], 0, 0, 0);
        __syncthreads();
    }

    // C/D layout: col = lane&15, row = quad*4 + reg
    #pragma unroll
    for (int i = 0; i < 4; ++i) {
        #pragma unroll
        for (int reg = 0; reg < 4; ++reg) {
            int m = m0 + wm0 + i * 16 + quad * 4 + reg;
            if (m >= M) continue;
            #pragma unroll
            for (int j = 0; j < 4; ++j) {
                int n = wn0 + j * 16 + ml;
                Cb[(size_t)m * 256 + n] = f2bf(acc[i][j][reg]);
            }
        }
    }

    // ---- fused attention logits: wave's 64 cols = head (wave&3) ----
    {
        int head = wave & 3;
        float alv[4], arv[4];
        #pragma unroll
        for (int j = 0; j < 4; ++j) {
            alv[j] = al[head * 64 + j * 16 + ml];
            arv[j] = ar[head * 64 + j * 16 + ml];
        }
        #pragma unroll
        for (int i = 0; i < 4; ++i) {
            #pragma unroll
            for (int reg = 0; reg < 4; ++reg) {
                float sl = 0.f, sr = 0.f;
                #pragma unroll
                for (int j = 0; j < 4; ++j) {
                    float v = acc[i][j][reg];
                    sl += v * alv[j];
                    sr += v * arv[j];
                }
                #pragma unroll
                for (int off = 1; off < 16; off <<= 1) {
                    sl += __shfl_xor(sl, off);
                    sr += __shfl_xor(sr, off);
                }
                int m = m0 + wm0 + i * 16 + quad * 4 + reg;
                if (ml == 0 && m < M) {
                    el[m * 4 + head] = sl;
                    er[m * 4 + head] = sr;
                }
            }
        }
    }
}

// ================= MFMA GEMM (128x128 tile) — used for the K=1024 output GEMM ======
__global__ __launch_bounds__(256) void gemm_bf16(const unsigned short* __restrict__ A,
                                                 const unsigned short* __restrict__ BT,
                                                 float* __restrict__ Cf,
                                                 int M, int Nout, int K) {
    __shared__ __align__(16) unsigned short Alds[128 * 32];
    __shared__ __align__(16) unsigned short Blds[128 * 32];
    const int tid = threadIdx.x;
    const int wave = tid >> 6;
    const int lane = tid & 63;
    const int quad = lane >> 4;
    const int ml = lane & 15;
    const int m0 = blockIdx.x * 128;
    const int n0 = blockIdx.y * 128;
    const int wm0 = (wave >> 1) * 64;
    const int wn0 = (wave & 1) * 64;

    const unsigned short* Ab = A + (size_t)(m0 + wave * 16 + (lane >> 2)) * K + (lane & 3) * 8;
    const unsigned short* Bb = BT + (size_t)(n0 + wave * 16 + (lane >> 2)) * K + (lane & 3) * 8;
    unsigned short* AldsW = Alds + wave * 512;
    unsigned short* BldsW = Blds + wave * 512;

    f32x4 acc[4][4] = {};

    for (int k0 = 0; k0 < K; k0 += 32) {
        #pragma unroll
        for (int p = 0; p < 2; ++p) {
            load_lds16(Ab + (size_t)(p * 64) * K + k0, AldsW + p * 2048);
            load_lds16(Bb + (size_t)(p * 64) * K + k0, BldsW + p * 2048);
        }
        __syncthreads();

        short8 af[4], bf[4];
        #pragma unroll
        for (int i = 0; i < 4; ++i)
            af[i] = *(const short8*)&Alds[(wm0 + i * 16 + ml) * 32 + quad * 8];
        #pragma unroll
        for (int j = 0; j < 4; ++j)
            bf[j] = *(const short8*)&Blds[(wn0 + j * 16 + ml) * 32 + quad * 8];
        #pragma unroll
        for (int i = 0; i < 4; ++i)
            #pragma unroll
            for (int j = 0; j < 4; ++j)
                acc[i][j] = __builtin_amdgcn_mfma_f32_16x16x32_bf16(af[i], bf[j], acc[i][j], 0, 0, 0);
        __syncthreads();
    }

    // C/D layout: col = lane&15, row = quad*4 + reg
    #pragma unroll
    for (int i = 0; i < 4; ++i) {
        #pragma unroll
        for (int reg = 0; reg < 4; ++reg) {
            int m = m0 + wm0 + i * 16 + quad * 4 + reg;
            if (m >= M) continue;
            #pragma unroll
            for (int j = 0; j < 4; ++j) {
                int n = n0 + wn0 + j * 16 + ml;
                if (n < Nout) Cf[(size_t)m * Nout + n] = acc[i][j][reg];
            }
        }
    }
}

// ======= CSR rowptr via block scan + atomic block-base; fills 8-pad slots inline ====
// pad ssrc -> sentinel row NN (feat zeros, el=-1e30 -> weight exp()=0); sdst=-1.
__global__ __launch_bounds__(256) void rowptr_k(const int* __restrict__ deg,
                                                int* __restrict__ rowptr,
                                                int* __restrict__ gtotal,
                                                int* __restrict__ ssrc,
                                                int* __restrict__ sdst) {
    __shared__ int sh[256];
    __shared__ int base;
    int i = blockIdx.x * 256 + threadIdx.x;
    int d = (i < NN) ? deg[i] : 0;
    int v = (d + 7) & ~7;
    sh[threadIdx.x] = v;
    __syncthreads();
    for (int off = 1; off < 256; off <<= 1) {
        int t = (threadIdx.x >= off) ? sh[threadIdx.x - off] : 0;
        __syncthreads();
        sh[threadIdx.x] += t;
        __syncthreads();
    }
    if (threadIdx.x == 255) base = atomicAdd(gtotal, sh[255]);
    __syncthreads();
    if (i < NN) {
        int rp = base + sh[threadIdx.x] - v;
        rowptr[i] = rp;
        for (int p = d; p < v; ++p) {   // <=7 pad slots
            ssrc[rp + p] = NN << 9;     // sentinel row
            sdst[rp + p] = -1;
        }
    }
}

// scatter: stores BYTE-SCALED src (src*512 = row byte offset in 256-ushort tables)
__global__ __launch_bounds__(256) void scatter_k(const int* __restrict__ src,
                                                 const int* __restrict__ dst,
                                                 const int* __restrict__ rowptr,
                                                 int* __restrict__ cursor,
                                                 int* __restrict__ ssrc,
                                                 int* __restrict__ sdst) {
    int e = blockIdx.x * blockDim.x + threadIdx.x;
    if (e >= NE) return;
    int d = dst[e];
    int p = atomicAdd(&cursor[d], 1);
    int pos = rowptr[d] + p;
    ssrc[pos] = src[e] << 9;
    sdst[pos] = d;
}

// ===== per-CSR-slot unnormalized weights, head-planar (layer 3 only) =====
// bounded by gtotal (allocated slots); pads (sdst<0) -> w=0.
__global__ __launch_bounds__(256) void edgew_k(const int* __restrict__ ssrc,
                                               const int* __restrict__ sdst,
                                               const int* __restrict__ gtotal,
                                               const float* __restrict__ el,
                                               const float* __restrict__ er,
                                               float* __restrict__ wcsr) {
    int i = blockIdx.x * blockDim.x + threadIdx.x;
    if (i >= gtotal[0]) return;
    int d = sdst[i];
    float w0 = 0.f, w1 = 0.f, w2 = 0.f, w3 = 0.f;
    if (d >= 0) {
        int su = ssrc[i];               // src*512; el row offset = src*16 = su>>5
        float4 e_l = *(const float4*)((const char*)el + (su >> 5));
        float4 e_r = *(const float4*)&er[d * 4];
        float v0 = e_l.x + e_r.x; v0 = fmaxf(v0, 0.2f * v0);
        float v1 = e_l.y + e_r.y; v1 = fmaxf(v1, 0.2f * v1);
        float v2 = e_l.z + e_r.z; v2 = fmaxf(v2, 0.2f * v2);
        float v3 = e_l.w + e_r.w; v3 = fmaxf(v3, 0.2f * v3);
        w0 = __expf(v0); w1 = __expf(v1); w2 = __expf(v2); w3 = __expf(v3);
    }
    wcsr[0 * MAXSLOT + i] = w0;
    wcsr[1 * MAXSLOT + i] = w1;
    wcsr[2 * MAXSLOT + i] = w2;
    wcsr[3 * MAXSLOT + i] = w3;
}

// ===== layers 1/2 aggregation: inline weights, NO pad masking (sentinel), 8-unroll ==
// el3/er3 (fused layer-3 logit outputs) MUST be disjoint from el/er (read here)!
__global__ __launch_bounds__(256) void agg256(const int* __restrict__ rowptr,
                                              const int* __restrict__ deg,
                                              const int* __restrict__ ssrc,
                                              const float* __restrict__ el,
                                              const float* __restrict__ er,
                                              const unsigned short* __restrict__ feat,
                                              unsigned short* __restrict__ ybf,
                                              const float* __restrict__ wl3,
                                              const float* __restrict__ wr3,
                                              float* __restrict__ el3,
                                              float* __restrict__ er3) {
    int wid = (blockIdx.x * blockDim.x + threadIdx.x) >> 6;
    int lane = threadIdx.x & 63;
    if (wid >= NN) return;
    int n = wid;
    int start = rowptr[n];
    int cnt8 = (deg[n] + 7) & ~7;
    int head = lane >> 4;
    float ern = er[n * 4 + head];
    const char* elb = (const char*)el + head * 4;   // + (src*16) per edge
    const char* fbase = (const char*)feat + lane * 8;
    f32x2 a01 = {0.f, 0.f}, a23 = {0.f, 0.f};
    float ssum = 0.f;
    for (int k = 0; k < cnt8; k += 8) {
        int4 sa = *(const int4*)&ssrc[start + k];       // wave-uniform -> scalar loads
        int4 sb = *(const int4*)&ssrc[start + k + 4];
        float e0 = *(const float*)(elb + (sa.x >> 5));
        float e1 = *(const float*)(elb + (sa.y >> 5));
        float e2 = *(const float*)(elb + (sa.z >> 5));
        float e3 = *(const float*)(elb + (sa.w >> 5));
        float e4 = *(const float*)(elb + (sb.x >> 5));
        float e5 = *(const float*)(elb + (sb.y >> 5));
        float e6 = *(const float*)(elb + (sb.z >> 5));
        float e7 = *(const float*)(elb + (sb.w >> 5));
        uint2 u0 = *(const uint2*)(fbase + sa.x);
        uint2 u1 = *(const uint2*)(fbase + sa.y);
        uint2 u2 = *(const uint2*)(fbase + sa.z);
        uint2 u3 = *(const uint2*)(fbase + sa.w);
        uint2 u4 = *(const uint2*)(fbase + sb.x);
        uint2 u5 = *(const uint2*)(fbase + sb.y);
        uint2 u6 = *(const uint2*)(fbase + sb.z);
        uint2 u7 = *(const uint2*)(fbase + sb.w);
        float v0 = e0 + ern; v0 = fmaxf(v0, 0.2f * v0); float w0 = __expf(v0);
        float v1 = e1 + ern; v1 = fmaxf(v1, 0.2f * v1); float w1 = __expf(v1);
        float v2 = e2 + ern; v2 = fmaxf(v2, 0.2f * v2); float w2 = __expf(v2);
        float v3 = e3 + ern; v3 = fmaxf(v3, 0.2f * v3); float w3 = __expf(v3);
        float v4 = e4 + ern; v4 = fmaxf(v4, 0.2f * v4); float w4 = __expf(v4);
        float v5 = e5 + ern; v5 = fmaxf(v5, 0.2f * v5); float w5 = __expf(v5);
        float v6 = e6 + ern; v6 = fmaxf(v6, 0.2f * v6); float w6 = __expf(v6);
        float v7 = e7 + ern; v7 = fmaxf(v7, 0.2f * v7); float w7 = __expf(v7);
        ssum += ((w0 + w1) + (w2 + w3)) + ((w4 + w5) + (w6 + w7));
        a01 += w0 * bfpair(u0.x); a23 += w0 * bfpair(u0.y);
        a01 += w1 * bfpair(u1.x); a23 += w1 * bfpair(u1.y);
        a01 += w2 * bfpair(u2.x); a23 += w2 * bfpair(u2.y);
        a01 += w3 * bfpair(u3.x); a23 += w3 * bfpair(u3.y);
        a01 += w4 * bfpair(u4.x); a23 += w4 * bfpair(u4.y);
        a01 += w5 * bfpair(u5.x); a23 += w5 * bfpair(u5.y);
        a01 += w6 * bfpair(u6.x); a23 += w6 * bfpair(u6.y);
        a01 += w7 * bfpair(u7.x); a23 += w7 * bfpair(u7.y);
    }
    float inv = ssum > 0.f ? 1.0f / ssum : 0.f;
    float r0 = a01.x * inv, r1 = a01.y * inv, r2 = a23.x * inv, r3 = a23.y * inv;
    r0 = r0 > 0.f ? r0 : (__expf(r0) - 1.f);
    r1 = r1 > 0.f ? r1 : (__expf(r1) - 1.f);
    r2 = r2 > 0.f ? r2 : (__expf(r2) - 1.f);
    r3 = r3 > 0.f ? r3 : (__expf(r3) - 1.f);
    ushort4 o;
    o.x = f2bf(r0); o.y = f2bf(r1); o.z = f2bf(r2); o.w = f2bf(r3);
    *(ushort4*)&ybf[(size_t)n * 256 + lane * 4] = o;

    // ---- fused layer-3 logits (layer-2 instance only; writes DISJOINT el3/er3) ----
    if (wl3) {
        float sl[4], sr[4];
        #pragma unroll
        for (int h = 0; h < 4; ++h) {
            float4 a4 = *(const float4*)&wl3[h * 256 + lane * 4];
            float4 b4 = *(const float4*)&wr3[h * 256 + lane * 4];
            sl[h] = r0 * a4.x + r1 * a4.y + r2 * a4.z + r3 * a4.w;
            sr[h] = r0 * b4.x + r1 * b4.y + r2 * b4.z + r3 * b4.w;
        }
        #pragma unroll
        for (int off = 32; off; off >>= 1) {
            #pragma unroll
            for (int h = 0; h < 4; ++h) {
                sl[h] += __shfl_xor(sl[h], off);
                sr[h] += __shfl_xor(sr[h], off);
            }
        }
        if (lane == 0) {
            #pragma unroll
            for (int h = 0; h < 4; ++h) {
                el3[n * 4 + h] = sl[h];
                er3[n * 4 + h] = sr[h];
            }
        }
    }
}

// ===== layer 3: aggregate x2 rows -> xagg[N][4][256] bf16, 8-edge unroll ===========
__global__ __launch_bounds__(256) void agg3(const int* __restrict__ rowptr,
                                            const int* __restrict__ deg,
                                            const int* __restrict__ ssrc,
                                            const float* __restrict__ wcsr,
                                            const unsigned short* __restrict__ x,
                                            unsigned short* __restrict__ xagg) {
    int wid = (blockIdx.x * blockDim.x + threadIdx.x) >> 6;
    int lane = threadIdx.x & 63;
    if (wid >= NN) return;
    int n = wid;
    int start = rowptr[n];
    int cnt8 = (deg[n] + 7) & ~7;
    const char* xbase = (const char*)x + lane * 8;
    f32x2 accA[4] = {}, accB[4] = {};
    float ssum[4] = {};
    for (int k = 0; k < cnt8; k += 8) {
        int4 sa = *(const int4*)&ssrc[start + k];
        int4 sb = *(const int4*)&ssrc[start + k + 4];
        float4 wa0 = *(const float4*)&wcsr[0 * MAXSLOT + start + k];
        float4 wa1 = *(const float4*)&wcsr[1 * MAXSLOT + start + k];
        float4 wa2 = *(const float4*)&wcsr[2 * MAXSLOT + start + k];
        float4 wa3 = *(const float4*)&wcsr[3 * MAXSLOT + start + k];
        float4 wb0 = *(const float4*)&wcsr[0 * MAXSLOT + start + k + 4];
        float4 wb1 = *(const float4*)&wcsr[1 * MAXSLOT + start + k + 4];
        float4 wb2 = *(const float4*)&wcsr[2 * MAXSLOT + start + k + 4];
        float4 wb3 = *(const float4*)&wcsr[3 * MAXSLOT + start + k + 4];
        uint2 u0 = *(const uint2*)(xbase + sa.x);
        uint2 u1 = *(const uint2*)(xbase + sa.y);
        uint2 u2 = *(const uint2*)(xbase + sa.z);
        uint2 u3 = *(const uint2*)(xbase + sa.w);
        uint2 u4 = *(const uint2*)(xbase + sb.x);
        uint2 u5 = *(const uint2*)(xbase + sb.y);
        uint2 u6 = *(const uint2*)(xbase + sb.z);
        uint2 u7 = *(const uint2*)(xbase + sb.w);
        ssum[0] += ((wa0.x + wa0.y) + (wa0.z + wa0.w)) + ((wb0.x + wb0.y) + (wb0.z + wb0.w));
        ssum[1] += ((wa1.x + wa1.y) + (wa1.z + wa1.w)) + ((wb1.x + wb1.y) + (wb1.z + wb1.w));
        ssum[2] += ((wa2.x + wa2.y) + (wa2.z + wa2.w)) + ((wb2.x + wb2.y) + (wb2.z + wb2.w));
        ssum[3] += ((wa3.x + wa3.y) + (wa3.z + wa3.w)) + ((wb3.x + wb3.y) + (wb3.z + wb3.w));
        f32x2 fa = bfpair(u0.x), fA = bfpair(u0.y);
        f32x2 fb = bfpair(u1.x), fB = bfpair(u1.y);
        f32x2 fc = bfpair(u2.x), fC = bfpair(u2.y);
        f32x2 fd = bfpair(u3.x), fD = bfpair(u3.y);
        f32x2 fe = bfpair(u4.x), fE = bfpair(u4.y);
        f32x2 ff = bfpair(u5.x), fF = bfpair(u5.y);
        f32x2 fg = bfpair(u6.x), fG = bfpair(u6.y);
        f32x2 fh = bfpair(u7.x), fH = bfpair(u7.y);
        accA[0] += wa0.x * fa + wa0.y * fb + wa0.z * fc + wa0.w * fd;
        accB[0] += wa0.x * fA + wa0.y * fB + wa0.z * fC + wa0.w * fD;
        accA[1] += wa1.x * fa + wa1.y * fb + wa1.z * fc + wa1.w * fd;
        accB[1] += wa1.x * fA + wa1.y * fB + wa1.z * fC + wa1.w * fD;
        accA[2] += wa2.x * fa + wa2.y * fb + wa2.z * fc + wa2.w * fd;
        accB[2] += wa2.x * fA + wa2.y * fB + wa2.z * fC + wa2.w * fD;
        accA[3] += wa3.x * fa + wa3.y * fb + wa3.z * fc + wa3.w * fd;
        accB[3] += wa3.x * fA + wa3.y * fB + wa3.z * fC + wa3.w * fD;
        accA[0] += wb0.x * fe + wb0.y * ff + wb0.z * fg + wb0.w * fh;
        accB[0] += wb0.x * fE + wb0.y * fF + wb0.z * fG + wb0.w * fH;
        accA[1] += wb1.x * fe + wb1.y * ff + wb1.z * fg + wb1.w * fh;
        accB[1] += wb1.x * fE + wb1.y * fF + wb1.z * fG + wb1.w * fH;
        accA[2] += wb2.x * fe + wb2.y * ff + wb2.z * fg + wb2.w * fh;
        accB[2] += wb2.x * fE + wb2.y * fF + wb2.z * fG + wb2.w * fH;
        accA[3] += wb3.x * fe + wb3.y * ff + wb3.z * fg + wb3.w * fh;
        accB[3] += wb3.x * fE + wb3.y * fF + wb3.z * fG + wb3.w * fH;
    }
    #pragma unroll
    for (int h = 0; h < 4; ++h) {
        float inv = ssum[h] > 0.f ? 1.f / ssum[h] : 0.f;
        ushort4 o;
        o.x = f2bf(accA[h].x * inv); o.y = f2bf(accA[h].y * inv);
        o.z = f2bf(accB[h].x * inv); o.w = f2bf(accB[h].y * inv);
        *(ushort4*)&xagg[(size_t)n * 1024 + h * 256 + lane * 4] = o;
    }
}

extern "C" void kernel_launch(void* const* d_in, const int* in_sizes, int n_in,
                              void* d_out, int out_size, void* d_ws, size_t ws_size,
                              hipStream_t stream) {
    const float* h   = (const float*)d_in[0];
    const int*   src = (const int*)d_in[1];
    const int*   dst = (const int*)d_in[2];
    const float* W1  = (const float*)d_in[3];
    const float* al1 = (const float*)d_in[4];
    const float* ar1 = (const float*)d_in[5];
    const float* W2  = (const float*)d_in[6];
    const float* al2 = (const float*)d_in[7];
    const float* ar2 = (const float*)d_in[8];
    const float* W3  = (const float*)d_in[9];
    const float* al3 = (const float*)d_in[10];
    const float* ar3 = (const float*)d_in[11];
    float* out = (float*)d_out;

    float* ws = (float*)d_ws;
    unsigned short* x_bf    = (unsigned short*)ws;
    unsigned short* h_bf    = (unsigned short*)(ws + 6400000);
    unsigned short* feat_bf = (unsigned short*)(ws + 12800000);  // +1 sentinel row
    unsigned short* xagg    = (unsigned short*)(ws + 6400000);   // overlays h_bf+feat_bf (dead by L3)
    float* el  = ws + 32000000;                  // 50001 rows x 4 (row NN = sentinel)
    float* er  = ws + 32200064;
    float* wl3 = ws + 32400064;
    float* wr3 = ws + 32401088;
    unsigned short* BT1   = (unsigned short*)(ws + 32402112);
    unsigned short* BT2   = (unsigned short*)(ws + 32434880);
    unsigned short* BTcat = (unsigned short*)(ws + 32467648);
    float* wcsr = ws + 32533184;                 // 4 x 800,000 floats (layer 3 only)
    int* ibase  = (int*)(ws + 35733184);
    int* deg      = ibase;                       // 50,000
    int* cursor   = ibase + 50000;               // 50,000 (adjacent: one memset)
    int* gtotal   = ibase + 100000;              // 1 (same memset range)
    int* rowptr   = ibase + 100256;              // 50,000
    int* ssrc     = ibase + 150256;              // 800,000 (byte-scaled src)
    int* sdst     = ibase + 950256;              // 800,000
    float* el2 = ws + 37483440;                  // 200,000 (layer-3 logits, DISJOINT from el)
    float* er2 = ws + 37683440;                  // 200,000

    const int NB = (NN + 255) / 256;
    const int SLOT_BLOCKS = (MAXSLOT + 255) / 256;

    // ---- single memset: deg + cursor + gtotal (pads handled inside rowptr_k) ----
    hipMemsetAsync(deg, 0, (2 * NN + 1) * sizeof(int), stream);

    // ---- fused prep: casts + weight prep + sentinel + dst histogram ----
    prep_k<<<(PREP_END + 255) / 256, 256, 0, stream>>>(h, W1, W2, W3, al3, ar3, dst,
                                                       h_bf, BT1, BT2, BTcat, wl3, wr3,
                                                       feat_bf, el, deg);

    // ---- CSR build: one scan kernel (atomic block base + inline pad-fill) ----
    rowptr_k<<<NB, 256, 0, stream>>>(deg, rowptr, gtotal, ssrc, sdst);
    scatter_k<<<(NE + 255) / 256, 256, 0, stream>>>(src, dst, rowptr, cursor, ssrc, sdst);

    const int GB = (NN + 127) / 128;             // 391 blocks, full 256-col tile
    const int WAVE_BLOCKS = (NN * 64 + 255) / 256;   // one wave per node

    // ---- layer 1 (agg computes edge weights inline from el/er; no pad masks) ----
    gemm256<<<GB, 512, 0, stream>>>(h_bf, BT1, feat_bf, al1, ar1, el, er, NN);
    agg256<<<WAVE_BLOCKS, 256, 0, stream>>>(rowptr, deg, ssrc, el, er, feat_bf, x_bf,
                                            nullptr, nullptr, nullptr, nullptr);

    // ---- layer 2 (fused layer-3 logit epilogue -> el2/er2, disjoint) ----
    gemm256<<<GB, 512, 0, stream>>>(x_bf, BT2, feat_bf, al2, ar2, el, er, NN);
    agg256<<<WAVE_BLOCKS, 256, 0, stream>>>(rowptr, deg, ssrc, el, er, feat_bf, x_bf,
                                            wl3, wr3, el2, er2);

    // ---- layer 3 (input-side aggregation; exact reorder of reference math) ----
    edgew_k<<<SLOT_BLOCKS, 256, 0, stream>>>(ssrc, sdst, gtotal, el2, er2, wcsr);
    agg3<<<WAVE_BLOCKS, 256, 0, stream>>>(rowptr, deg, ssrc, wcsr, x_bf, xagg);
    gemm_bf16<<<dim3(GB, 1), 256, 0, stream>>>(xagg, BTcat, out, NN, NC, 1024);
}

// Round 10
// 376.072 us; speedup vs baseline: 1.0323x; 1.0323x over previous
//
#include <hip/hip_runtime.h>
#include <cstddef>

#define NN 50000
#define NE 400000
#define NH 4
#define NC 121
#define MAXSLOT 600000   // NE + 4*NN upper bound on 4-padded CSR slots

typedef __attribute__((ext_vector_type(8))) short short8;
typedef __attribute__((ext_vector_type(4))) float f32x4;
typedef __attribute__((ext_vector_type(2))) float f32x2;

// fp32 -> bf16 round-to-nearest-even
static __device__ __forceinline__ unsigned short f2bf(float f) {
    unsigned u = __float_as_uint(f);
    u += 0x7fffu + ((u >> 16) & 1u);
    return (unsigned short)(u >> 16);
}
// dword holding 2 bf16 -> 2 floats
static __device__ __forceinline__ f32x2 bfpair(unsigned u) {
    f32x2 r;
    r.x = __uint_as_float(u << 16);
    r.y = __uint_as_float(u & 0xffff0000u);
    return r;
}
// async global->LDS, 16B per lane; LDS dest = wave-uniform base + lane*16
static __device__ __forceinline__ void load_lds16(const unsigned short* g, unsigned short* l) {
    __builtin_amdgcn_global_load_lds(
        (const __attribute__((address_space(1))) unsigned*)g,
        (__attribute__((address_space(3))) unsigned*)l, 16, 0, 0);
}

// == fused prep: cast_x + BT1 + BT2 + BTcat + wvec3 + sentinel + dst histogram ======
#define PREP_X    3200000            // NN*256/4 float4->ushort4 items
#define PREP_BT1  (PREP_X + 65536)
#define PREP_BT2  (PREP_BT1 + 65536)
#define PREP_CAT  (PREP_BT2 + 131072)
#define PREP_WV   (PREP_CAT + 2048)
#define PREP_SENT (PREP_WV + 256)
#define PREP_END  (PREP_SENT + NE)
__global__ __launch_bounds__(256) void prep_k(const float* __restrict__ h,
                                              const float* __restrict__ W1,
                                              const float* __restrict__ W2,
                                              const float* __restrict__ W3,
                                              const float* __restrict__ al3,
                                              const float* __restrict__ ar3,
                                              const int* __restrict__ dst,
                                              unsigned short* __restrict__ h_bf,
                                              unsigned short* __restrict__ BT1,
                                              unsigned short* __restrict__ BT2,
                                              unsigned short* __restrict__ BTcat,
                                              float* __restrict__ wl3,
                                              float* __restrict__ wr3,
                                              unsigned short* __restrict__ feat_bf,
                                              float* __restrict__ el,
                                              int* __restrict__ deg) {
    int i = blockIdx.x * blockDim.x + threadIdx.x;
    if (i < PREP_X) {
        float4 v = *(const float4*)&h[(size_t)i * 4];
        ushort4 o;
        o.x = f2bf(v.x); o.y = f2bf(v.y); o.z = f2bf(v.z); o.w = f2bf(v.w);
        *(ushort4*)&h_bf[(size_t)i * 4] = o;
    } else if (i < PREP_BT1) {
        int j = i - PREP_X;
        int n = j >> 8, k = j & 255;
        BT1[j] = f2bf(W1[(size_t)k * 256 + n]);
    } else if (i < PREP_BT2) {
        int j = i - PREP_BT1;
        int n = j >> 8, k = j & 255;
        BT2[j] = f2bf(W2[(size_t)k * 256 + n]);
    } else if (i < PREP_CAT) {
        // BTcat[c][kk]: c = class (121, pad to 128 rows), kk = h*256 + k (K=1024)
        // value = 0.25 * W3[k, h*121 + c]  (0.25 = mean over heads, folded in)
        int j = i - PREP_BT2;
        int c = j >> 10, kk = j & 1023;
        int hh = kk >> 8, k = kk & 255;
        float v = (c < NC) ? 0.25f * W3[(size_t)k * 484 + hh * NC + c] : 0.f;
        BTcat[j] = f2bf(v);
    } else if (i < PREP_WV) {
        int j = (i - PREP_CAT) & 1023;
        int sel = (i - PREP_CAT) >> 10;
        int hh = j >> 8, k = j & 255;
        const float* a = sel ? ar3 : al3;
        const float* wrow = W3 + (size_t)k * 484 + hh * NC;
        const float* arow = a + hh * NC;
        float s = 0.f;
        for (int d = 0; d < NC; ++d) s += wrow[d] * arow[d];
        if (sel) wr3[j] = s; else wl3[j] = s;
    } else if (i < PREP_SENT) {
        // sentinel row NN: feat_bf[NN][*] = 0 (pad gathers read zeros);
        // el[NN][h] = -1e30 (pad logits -> exp = 0 -> no masking in agg256)
        int j = i - PREP_WV;
        feat_bf[(size_t)NN * 256 + j] = 0;
        if (j < 4) el[NN * 4 + j] = -1e30f;
    } else if (i < PREP_END) {
        atomicAdd(&deg[dst[i - PREP_SENT]], 1);
    }
}

// ====== 8-wave 128x256 MFMA GEMM for layers 1/2 (N=256, K=256): A read ONCE ======
// Wave w computes 64x64 quadrant (wm=(w>>2)*64, wn=(w&3)*64). Fused logit epilogue:
// wave's 64 output cols = one head (head = w&3).
__global__ __launch_bounds__(512) void gemm256(const unsigned short* __restrict__ A,
                                               const unsigned short* __restrict__ BT,
                                               unsigned short* __restrict__ Cb,
                                               const float* __restrict__ al,
                                               const float* __restrict__ ar,
                                               float* __restrict__ el,
                                               float* __restrict__ er,
                                               int M) {
    const int K = 256;
    __shared__ __align__(16) unsigned short Alds[128 * 32];
    __shared__ __align__(16) unsigned short Blds[256 * 32];
    const int tid = threadIdx.x;
    const int wave = tid >> 6;
    const int lane = tid & 63;
    const int quad = lane >> 4;
    const int ml = lane & 15;
    const int m0 = blockIdx.x * 128;
    const int wm0 = (wave >> 2) * 64;
    const int wn0 = (wave & 3) * 64;

    const unsigned short* Ab = A + (size_t)(m0 + wave * 16 + (lane >> 2)) * K + (lane & 3) * 8;
    const unsigned short* Bb = BT + (size_t)(wave * 16 + (lane >> 2)) * K + (lane & 3) * 8;
    unsigned short* AldsW = Alds + wave * 512;
    unsigned short* BldsW = Blds + wave * 512;

    f32x4 acc[4][4] = {};

    for (int k0 = 0; k0 < K; k0 += 32) {
        load_lds16(Ab + k0, AldsW);
        #pragma unroll
        for (int p = 0; p < 2; ++p)
            load_lds16(Bb + (size_t)(p * 128) * K + k0, BldsW + p * 4096);
        __syncthreads();

        short8 af[4], bf[4];
        #pragma unroll
        for (int i = 0; i < 4; ++i)
            af[i] = *(const short8*)&Alds[(wm0 + i * 16 + ml) * 32 + quad * 8];
        #pragma unroll
        for (int j = 0; j < 4; ++j)
            bf[j] = *(const short8*)&Blds[(wn0 + j * 16 + ml) * 32 + quad * 8];
        #pragma unroll
        for (int i = 0; i < 4; ++i)
            #pragma unroll
            for (int j = 0; j < 4; ++j)
                acc[i][j] = __builtin_amdgcn_mfma_f32_16x16x32_bf16(af[i], bf[j], acc[i][j], 0, 0, 0);
        __syncthreads();
    }

    // C/D layout: col = lane&15, row = quad*4 + reg
    #pragma unroll
    for (int i = 0; i < 4; ++i) {
        #pragma unroll
        for (int reg = 0; reg < 4; ++reg) {
            int m = m0 + wm0 + i * 16 + quad * 4 + reg;
            if (m >= M) continue;
            #pragma unroll
            for (int j = 0; j < 4; ++j) {
                int n = wn0 + j * 16 + ml;
                Cb[(size_t)m * 256 + n] = f2bf(acc[i][j][reg]);
            }
        }
    }

    // ---- fused attention logits: wave's 64 cols = head (wave&3) ----
    {
        int head = wave & 3;
        float alv[4], arv[4];
        #pragma unroll
        for (int j = 0; j < 4; ++j) {
            alv[j] = al[head * 64 + j * 16 + ml];
            arv[j] = ar[head * 64 + j * 16 + ml];
        }
        #pragma unroll
        for (int i = 0; i < 4; ++i) {
            #pragma unroll
            for (int reg = 0; reg < 4; ++reg) {
                float sl = 0.f, sr = 0.f;
                #pragma unroll
                for (int j = 0; j < 4; ++j) {
                    float v = acc[i][j][reg];
                    sl += v * alv[j];
                    sr += v * arv[j];
                }
                #pragma unroll
                for (int off = 1; off < 16; off <<= 1) {
                    sl += __shfl_xor(sl, off);
                    sr += __shfl_xor(sr, off);
                }
                int m = m0 + wm0 + i * 16 + quad * 4 + reg;
                if (ml == 0 && m < M) {
                    el[m * 4 + head] = sl;
                    er[m * 4 + head] = sr;
                }
            }
        }
    }
}

// ================= MFMA GEMM (128x128 tile) — used for the K=1024 output GEMM ======
__global__ __launch_bounds__(256) void gemm_bf16(const unsigned short* __restrict__ A,
                                                 const unsigned short* __restrict__ BT,
                                                 float* __restrict__ Cf,
                                                 int M, int Nout, int K) {
    __shared__ __align__(16) unsigned short Alds[128 * 32];
    __shared__ __align__(16) unsigned short Blds[128 * 32];
    const int tid = threadIdx.x;
    const int wave = tid >> 6;
    const int lane = tid & 63;
    const int quad = lane >> 4;
    const int ml = lane & 15;
    const int m0 = blockIdx.x * 128;
    const int n0 = blockIdx.y * 128;
    const int wm0 = (wave >> 1) * 64;
    const int wn0 = (wave & 1) * 64;

    const unsigned short* Ab = A + (size_t)(m0 + wave * 16 + (lane >> 2)) * K + (lane & 3) * 8;
    const unsigned short* Bb = BT + (size_t)(n0 + wave * 16 + (lane >> 2)) * K + (lane & 3) * 8;
    unsigned short* AldsW = Alds + wave * 512;
    unsigned short* BldsW = Blds + wave * 512;

    f32x4 acc[4][4] = {};

    for (int k0 = 0; k0 < K; k0 += 32) {
        #pragma unroll
        for (int p = 0; p < 2; ++p) {
            load_lds16(Ab + (size_t)(p * 64) * K + k0, AldsW + p * 2048);
            load_lds16(Bb + (size_t)(p * 64) * K + k0, BldsW + p * 2048);
        }
        __syncthreads();

        short8 af[4], bf[4];
        #pragma unroll
        for (int i = 0; i < 4; ++i)
            af[i] = *(const short8*)&Alds[(wm0 + i * 16 + ml) * 32 + quad * 8];
        #pragma unroll
        for (int j = 0; j < 4; ++j)
            bf[j] = *(const short8*)&Blds[(wn0 + j * 16 + ml) * 32 + quad * 8];
        #pragma unroll
        for (int i = 0; i < 4; ++i)
            #pragma unroll
            for (int j = 0; j < 4; ++j)
                acc[i][j] = __builtin_amdgcn_mfma_f32_16x16x32_bf16(af[i], bf[j], acc[i][j], 0, 0, 0);
        __syncthreads();
    }

    // C/D layout: col = lane&15, row = quad*4 + reg
    #pragma unroll
    for (int i = 0; i < 4; ++i) {
        #pragma unroll
        for (int reg = 0; reg < 4; ++reg) {
            int m = m0 + wm0 + i * 16 + quad * 4 + reg;
            if (m >= M) continue;
            #pragma unroll
            for (int j = 0; j < 4; ++j) {
                int n = n0 + wn0 + j * 16 + ml;
                if (n < Nout) Cf[(size_t)m * Nout + n] = acc[i][j][reg];
            }
        }
    }
}

// ======= CSR rowptr via block scan + atomic block-base; fills 4-pad slots inline ====
// pad ssrc -> sentinel row NN (feat zeros, el=-1e30 -> weight exp()=0); sdst=-1.
__global__ __launch_bounds__(256) void rowptr_k(const int* __restrict__ deg,
                                                int* __restrict__ rowptr,
                                                int* __restrict__ gtotal,
                                                int* __restrict__ ssrc,
                                                int* __restrict__ sdst) {
    __shared__ int sh[256];
    __shared__ int base;
    int i = blockIdx.x * 256 + threadIdx.x;
    int d = (i < NN) ? deg[i] : 0;
    int v = (d + 3) & ~3;
    sh[threadIdx.x] = v;
    __syncthreads();
    for (int off = 1; off < 256; off <<= 1) {
        int t = (threadIdx.x >= off) ? sh[threadIdx.x - off] : 0;
        __syncthreads();
        sh[threadIdx.x] += t;
        __syncthreads();
    }
    if (threadIdx.x == 255) base = atomicAdd(gtotal, sh[255]);
    __syncthreads();
    if (i < NN) {
        int rp = base + sh[threadIdx.x] - v;
        rowptr[i] = rp;
        for (int p = d; p < v; ++p) {   // <=3 pad slots
            ssrc[rp + p] = NN << 9;     // sentinel row
            sdst[rp + p] = -1;
        }
    }
}

// scatter: stores BYTE-SCALED src (src*512 = row byte offset in 256-ushort tables)
__global__ __launch_bounds__(256) void scatter_k(const int* __restrict__ src,
                                                 const int* __restrict__ dst,
                                                 const int* __restrict__ rowptr,
                                                 int* __restrict__ cursor,
                                                 int* __restrict__ ssrc,
                                                 int* __restrict__ sdst) {
    int e = blockIdx.x * blockDim.x + threadIdx.x;
    if (e >= NE) return;
    int d = dst[e];
    int p = atomicAdd(&cursor[d], 1);
    int pos = rowptr[d] + p;
    ssrc[pos] = src[e] << 9;
    sdst[pos] = d;
}

// ===== per-CSR-slot unnormalized weights, head-planar (layer 3 only) =====
// bounded by gtotal (allocated slots); pads (sdst<0) -> w=0.
__global__ __launch_bounds__(256) void edgew_k(const int* __restrict__ ssrc,
                                               const int* __restrict__ sdst,
                                               const int* __restrict__ gtotal,
                                               const float* __restrict__ el,
                                               const float* __restrict__ er,
                                               float* __restrict__ wcsr) {
    int i = blockIdx.x * blockDim.x + threadIdx.x;
    if (i >= gtotal[0]) return;
    int d = sdst[i];
    float w0 = 0.f, w1 = 0.f, w2 = 0.f, w3 = 0.f;
    if (d >= 0) {
        int su = ssrc[i];               // src*512; el row offset = src*16 = su>>5
        float4 e_l = *(const float4*)((const char*)el + (su >> 5));
        float4 e_r = *(const float4*)&er[d * 4];
        float v0 = e_l.x + e_r.x; v0 = fmaxf(v0, 0.2f * v0);
        float v1 = e_l.y + e_r.y; v1 = fmaxf(v1, 0.2f * v1);
        float v2 = e_l.z + e_r.z; v2 = fmaxf(v2, 0.2f * v2);
        float v3 = e_l.w + e_r.w; v3 = fmaxf(v3, 0.2f * v3);
        w0 = __expf(v0); w1 = __expf(v1); w2 = __expf(v2); w3 = __expf(v3);
    }
    wcsr[0 * MAXSLOT + i] = w0;
    wcsr[1 * MAXSLOT + i] = w1;
    wcsr[2 * MAXSLOT + i] = w2;
    wcsr[3 * MAXSLOT + i] = w3;
}

// ===== layers 1/2 aggregation: inline weights, sentinel pads (no masking), 4-unroll =
// el3/er3 (fused layer-3 logit outputs) MUST be disjoint from el/er (read here)!
__global__ __launch_bounds__(256) void agg256(const int* __restrict__ rowptr,
                                              const int* __restrict__ deg,
                                              const int* __restrict__ ssrc,
                                              const float* __restrict__ el,
                                              const float* __restrict__ er,
                                              const unsigned short* __restrict__ feat,
                                              unsigned short* __restrict__ ybf,
                                              const float* __restrict__ wl3,
                                              const float* __restrict__ wr3,
                                              float* __restrict__ el3,
                                              float* __restrict__ er3) {
    int wid = (blockIdx.x * blockDim.x + threadIdx.x) >> 6;
    int lane = threadIdx.x & 63;
    if (wid >= NN) return;
    int n = wid;
    int start = rowptr[n];
    int cnt4 = (deg[n] + 3) & ~3;
    int head = lane >> 4;
    float ern = er[n * 4 + head];
    const char* elb = (const char*)el + head * 4;   // + (src*16) per edge
    const char* fbase = (const char*)feat + lane * 8;
    f32x2 a01 = {0.f, 0.f}, a23 = {0.f, 0.f};
    float ssum = 0.f;
    for (int k = 0; k < cnt4; k += 4) {
        int4 sv = *(const int4*)&ssrc[start + k];   // wave-uniform -> scalar loads
        float e0 = *(const float*)(elb + (sv.x >> 5));
        float e1 = *(const float*)(elb + (sv.y >> 5));
        float e2 = *(const float*)(elb + (sv.z >> 5));
        float e3 = *(const float*)(elb + (sv.w >> 5));
        float v0 = e0 + ern; v0 = fmaxf(v0, 0.2f * v0); float w0 = __expf(v0);
        float v1 = e1 + ern; v1 = fmaxf(v1, 0.2f * v1); float w1 = __expf(v1);
        float v2 = e2 + ern; v2 = fmaxf(v2, 0.2f * v2); float w2 = __expf(v2);
        float v3 = e3 + ern; v3 = fmaxf(v3, 0.2f * v3); float w3 = __expf(v3);
        uint2 u0 = *(const uint2*)(fbase + sv.x);
        uint2 u1 = *(const uint2*)(fbase + sv.y);
        uint2 u2 = *(const uint2*)(fbase + sv.z);
        uint2 u3 = *(const uint2*)(fbase + sv.w);
        ssum += (w0 + w1) + (w2 + w3);
        a01 += w0 * bfpair(u0.x); a23 += w0 * bfpair(u0.y);
        a01 += w1 * bfpair(u1.x); a23 += w1 * bfpair(u1.y);
        a01 += w2 * bfpair(u2.x); a23 += w2 * bfpair(u2.y);
        a01 += w3 * bfpair(u3.x); a23 += w3 * bfpair(u3.y);
    }
    float inv = ssum > 0.f ? 1.0f / ssum : 0.f;
    float r0 = a01.x * inv, r1 = a01.y * inv, r2 = a23.x * inv, r3 = a23.y * inv;
    r0 = r0 > 0.f ? r0 : (__expf(r0) - 1.f);
    r1 = r1 > 0.f ? r1 : (__expf(r1) - 1.f);
    r2 = r2 > 0.f ? r2 : (__expf(r2) - 1.f);
    r3 = r3 > 0.f ? r3 : (__expf(r3) - 1.f);
    ushort4 o;
    o.x = f2bf(r0); o.y = f2bf(r1); o.z = f2bf(r2); o.w = f2bf(r3);
    *(ushort4*)&ybf[(size_t)n * 256 + lane * 4] = o;

    // ---- fused layer-3 logits (layer-2 instance only; writes DISJOINT el3/er3) ----
    if (wl3) {
        float sl[4], sr[4];
        #pragma unroll
        for (int h = 0; h < 4; ++h) {
            float4 a4 = *(const float4*)&wl3[h * 256 + lane * 4];
            float4 b4 = *(const float4*)&wr3[h * 256 + lane * 4];
            sl[h] = r0 * a4.x + r1 * a4.y + r2 * a4.z + r3 * a4.w;
            sr[h] = r0 * b4.x + r1 * b4.y + r2 * b4.z + r3 * b4.w;
        }
        #pragma unroll
        for (int off = 32; off; off >>= 1) {
            #pragma unroll
            for (int h = 0; h < 4; ++h) {
                sl[h] += __shfl_xor(sl[h], off);
                sr[h] += __shfl_xor(sr[h], off);
            }
        }
        if (lane == 0) {
            #pragma unroll
            for (int h = 0; h < 4; ++h) {
                el3[n * 4 + h] = sl[h];
                er3[n * 4 + h] = sr[h];
            }
        }
    }
}

// ===== layer 3: aggregate x2 rows -> xagg[N][4][256] bf16, 4-edge unroll (36 VGPR) ==
__global__ __launch_bounds__(256) void agg3(const int* __restrict__ rowptr,
                                            const int* __restrict__ deg,
                                            const int* __restrict__ ssrc,
                                            const float* __restrict__ wcsr,
                                            const unsigned short* __restrict__ x,
                                            unsigned short* __restrict__ xagg) {
    int wid = (blockIdx.x * blockDim.x + threadIdx.x) >> 6;
    int lane = threadIdx.x & 63;
    if (wid >= NN) return;
    int n = wid;
    int start = rowptr[n];
    int cnt4 = (deg[n] + 3) & ~3;
    const char* xbase = (const char*)x + lane * 8;
    f32x2 accA[4] = {}, accB[4] = {};
    float ssum[4] = {};
    for (int k = 0; k < cnt4; k += 4) {
        int4 sv = *(const int4*)&ssrc[start + k];
        float4 w0 = *(const float4*)&wcsr[0 * MAXSLOT + start + k];
        float4 w1 = *(const float4*)&wcsr[1 * MAXSLOT + start + k];
        float4 w2 = *(const float4*)&wcsr[2 * MAXSLOT + start + k];
        float4 w3 = *(const float4*)&wcsr[3 * MAXSLOT + start + k];
        uint2 u0 = *(const uint2*)(xbase + sv.x);
        uint2 u1 = *(const uint2*)(xbase + sv.y);
        uint2 u2 = *(const uint2*)(xbase + sv.z);
        uint2 u3 = *(const uint2*)(xbase + sv.w);
        ssum[0] += (w0.x + w0.y) + (w0.z + w0.w);
        ssum[1] += (w1.x + w1.y) + (w1.z + w1.w);
        ssum[2] += (w2.x + w2.y) + (w2.z + w2.w);
        ssum[3] += (w3.x + w3.y) + (w3.z + w3.w);
        f32x2 fa = bfpair(u0.x), fA = bfpair(u0.y);
        f32x2 fb = bfpair(u1.x), fB = bfpair(u1.y);
        f32x2 fc = bfpair(u2.x), fC = bfpair(u2.y);
        f32x2 fd = bfpair(u3.x), fD = bfpair(u3.y);
        accA[0] += w0.x * fa + w0.y * fb + w0.z * fc + w0.w * fd;
        accB[0] += w0.x * fA + w0.y * fB + w0.z * fC + w0.w * fD;
        accA[1] += w1.x * fa + w1.y * fb + w1.z * fc + w1.w * fd;
        accB[1] += w1.x * fA + w1.y * fB + w1.z * fC + w1.w * fD;
        accA[2] += w2.x * fa + w2.y * fb + w2.z * fc + w2.w * fd;
        accB[2] += w2.x * fA + w2.y * fB + w2.z * fC + w2.w * fD;
        accA[3] += w3.x * fa + w3.y * fb + w3.z * fc + w3.w * fd;
        accB[3] += w3.x * fA + w3.y * fB + w3.z * fC + w3.w * fD;
    }
    #pragma unroll
    for (int h = 0; h < 4; ++h) {
        float inv = ssum[h] > 0.f ? 1.f / ssum[h] : 0.f;
        ushort4 o;
        o.x = f2bf(accA[h].x * inv); o.y = f2bf(accA[h].y * inv);
        o.z = f2bf(accB[h].x * inv); o.w = f2bf(accB[h].y * inv);
        *(ushort4*)&xagg[(size_t)n * 1024 + h * 256 + lane * 4] = o;
    }
}

extern "C" void kernel_launch(void* const* d_in, const int* in_sizes, int n_in,
                              void* d_out, int out_size, void* d_ws, size_t ws_size,
                              hipStream_t stream) {
    const float* h   = (const float*)d_in[0];
    const int*   src = (const int*)d_in[1];
    const int*   dst = (const int*)d_in[2];
    const float* W1  = (const float*)d_in[3];
    const float* al1 = (const float*)d_in[4];
    const float* ar1 = (const float*)d_in[5];
    const float* W2  = (const float*)d_in[6];
    const float* al2 = (const float*)d_in[7];
    const float* ar2 = (const float*)d_in[8];
    const float* W3  = (const float*)d_in[9];
    const float* al3 = (const float*)d_in[10];
    const float* ar3 = (const float*)d_in[11];
    float* out = (float*)d_out;

    float* ws = (float*)d_ws;
    unsigned short* x_bf    = (unsigned short*)ws;
    unsigned short* h_bf    = (unsigned short*)(ws + 6400000);
    unsigned short* feat_bf = (unsigned short*)(ws + 12800000);  // +1 sentinel row
    unsigned short* xagg    = (unsigned short*)(ws + 6400000);   // overlays h_bf+feat_bf (dead by L3)
    float* el  = ws + 32000000;                  // 50001 rows x 4 (row NN = sentinel)
    float* er  = ws + 32200064;
    float* wl3 = ws + 32400064;
    float* wr3 = ws + 32401088;
    unsigned short* BT1   = (unsigned short*)(ws + 32402112);
    unsigned short* BT2   = (unsigned short*)(ws + 32434880);
    unsigned short* BTcat = (unsigned short*)(ws + 32467648);
    float* wcsr = ws + 32533184;                 // 4 x 600,000 floats (layer 3 only)
    int* ibase  = (int*)(ws + 34933184);
    int* deg      = ibase;                       // 50,000
    int* cursor   = ibase + 50000;               // 50,000 (adjacent: one memset)
    int* gtotal   = ibase + 100000;              // 1 (same memset range)
    int* rowptr   = ibase + 100256;              // 50,000
    int* ssrc     = ibase + 150256;              // 600,000 (byte-scaled src)
    int* sdst     = ibase + 750256;              // 600,000
    float* el2 = ws + 36283440;                  // 200,000 (layer-3 logits, DISJOINT from el)
    float* er2 = ws + 36483440;                  // 200,000

    const int NB = (NN + 255) / 256;
    const int SLOT_BLOCKS = (MAXSLOT + 255) / 256;

    // ---- single memset: deg + cursor + gtotal (pads handled inside rowptr_k) ----
    hipMemsetAsync(deg, 0, (2 * NN + 1) * sizeof(int), stream);

    // ---- fused prep: casts + weight prep + sentinel + dst histogram ----
    prep_k<<<(PREP_END + 255) / 256, 256, 0, stream>>>(h, W1, W2, W3, al3, ar3, dst,
                                                       h_bf, BT1, BT2, BTcat, wl3, wr3,
                                                       feat_bf, el, deg);

    // ---- CSR build: one scan kernel (atomic block base + inline pad-fill) ----
    rowptr_k<<<NB, 256, 0, stream>>>(deg, rowptr, gtotal, ssrc, sdst);
    scatter_k<<<(NE + 255) / 256, 256, 0, stream>>>(src, dst, rowptr, cursor, ssrc, sdst);

    const int GB = (NN + 127) / 128;             // 391 blocks, full 256-col tile
    const int WAVE_BLOCKS = (NN * 64 + 255) / 256;   // one wave per node

    // ---- layer 1 (agg computes edge weights inline from el/er; sentinel pads) ----
    gemm256<<<GB, 512, 0, stream>>>(h_bf, BT1, feat_bf, al1, ar1, el, er, NN);
    agg256<<<WAVE_BLOCKS, 256, 0, stream>>>(rowptr, deg, ssrc, el, er, feat_bf, x_bf,
                                            nullptr, nullptr, nullptr, nullptr);

    // ---- layer 2 (fused layer-3 logit epilogue -> el2/er2, disjoint) ----
    gemm256<<<GB, 512, 0, stream>>>(x_bf, BT2, feat_bf, al2, ar2, el, er, NN);
    agg256<<<WAVE_BLOCKS, 256, 0, stream>>>(rowptr, deg, ssrc, el, er, feat_bf, x_bf,
                                            wl3, wr3, el2, er2);

    // ---- layer 3 (input-side aggregation; exact reorder of reference math) ----
    edgew_k<<<SLOT_BLOCKS, 256, 0, stream>>>(ssrc, sdst, gtotal, el2, er2, wcsr);
    agg3<<<WAVE_BLOCKS, 256, 0, stream>>>(rowptr, deg, ssrc, wcsr, x_bf, xagg);
    gemm_bf16<<<dim3(GB, 1), 256, 0, stream>>>(xagg, BTcat, out, NN, NC, 1024);
}

// Round 11
// 370.723 us; speedup vs baseline: 1.0472x; 1.0144x over previous
//
#include <hip/hip_runtime.h>
#include <cstddef>

#define NN 50000
#define NE 400000
#define NH 4
#define NC 121

typedef __attribute__((ext_vector_type(8))) short short8;
typedef __attribute__((ext_vector_type(4))) float f32x4;
typedef __attribute__((ext_vector_type(2))) float f32x2;

// fp32 -> bf16 round-to-nearest-even
static __device__ __forceinline__ unsigned short f2bf(float f) {
    unsigned u = __float_as_uint(f);
    u += 0x7fffu + ((u >> 16) & 1u);
    return (unsigned short)(u >> 16);
}
// dword holding 2 bf16 -> 2 floats
static __device__ __forceinline__ f32x2 bfpair(unsigned u) {
    f32x2 r;
    r.x = __uint_as_float(u << 16);
    r.y = __uint_as_float(u & 0xffff0000u);
    return r;
}
// async global->LDS, 16B per lane; LDS dest = wave-uniform base + lane*16
static __device__ __forceinline__ void load_lds16(const unsigned short* g, unsigned short* l) {
    __builtin_amdgcn_global_load_lds(
        (const __attribute__((address_space(1))) unsigned*)g,
        (__attribute__((address_space(3))) unsigned*)l, 16, 0, 0);
}

// == fused prep: cast_x + BT1 + BT2 + BTcat + wvec3 + sentinels + dst histogram =====
#define PREP_X    3200000            // NN*256/4 float4->ushort4 items
#define PREP_BT1  (PREP_X + 65536)
#define PREP_BT2  (PREP_BT1 + 65536)
#define PREP_CAT  (PREP_BT2 + 131072)
#define PREP_WV   (PREP_CAT + 2048)
#define PREP_SENT (PREP_WV + 256)
#define PREP_END  (PREP_SENT + NE)
__global__ __launch_bounds__(256) void prep_k(const float* __restrict__ h,
                                              const float* __restrict__ W1,
                                              const float* __restrict__ W2,
                                              const float* __restrict__ W3,
                                              const float* __restrict__ al3,
                                              const float* __restrict__ ar3,
                                              const int* __restrict__ dst,
                                              unsigned short* __restrict__ h_bf,
                                              unsigned short* __restrict__ BT1,
                                              unsigned short* __restrict__ BT2,
                                              unsigned short* __restrict__ BTcat,
                                              float* __restrict__ wl3,
                                              float* __restrict__ wr3,
                                              unsigned short* __restrict__ feat_bf,
                                              float* __restrict__ el,
                                              float* __restrict__ el2,
                                              int* __restrict__ deg) {
    int i = blockIdx.x * blockDim.x + threadIdx.x;
    if (i < PREP_X) {
        float4 v = *(const float4*)&h[(size_t)i * 4];
        ushort4 o;
        o.x = f2bf(v.x); o.y = f2bf(v.y); o.z = f2bf(v.z); o.w = f2bf(v.w);
        *(ushort4*)&h_bf[(size_t)i * 4] = o;
    } else if (i < PREP_BT1) {
        int j = i - PREP_X;
        int n = j >> 8, k = j & 255;
        BT1[j] = f2bf(W1[(size_t)k * 256 + n]);
    } else if (i < PREP_BT2) {
        int j = i - PREP_BT1;
        int n = j >> 8, k = j & 255;
        BT2[j] = f2bf(W2[(size_t)k * 256 + n]);
    } else if (i < PREP_CAT) {
        // BTcat[c][kk]: c = class (121, pad to 128 rows), kk = h*256 + k (K=1024)
        // value = 0.25 * W3[k, h*121 + c]  (0.25 = mean over heads, folded in)
        int j = i - PREP_BT2;
        int c = j >> 10, kk = j & 1023;
        int hh = kk >> 8, k = kk & 255;
        float v = (c < NC) ? 0.25f * W3[(size_t)k * 484 + hh * NC + c] : 0.f;
        BTcat[j] = f2bf(v);
    } else if (i < PREP_WV) {
        int j = (i - PREP_CAT) & 1023;
        int sel = (i - PREP_CAT) >> 10;
        int hh = j >> 8, k = j & 255;
        const float* a = sel ? ar3 : al3;
        const float* wrow = W3 + (size_t)k * 484 + hh * NC;
        const float* arow = a + hh * NC;
        float s = 0.f;
        for (int d = 0; d < NC; ++d) s += wrow[d] * arow[d];
        if (sel) wr3[j] = s; else wl3[j] = s;
    } else if (i < PREP_SENT) {
        // sentinel row NN: feat_bf[NN][*] = 0 (pad gathers read zeros);
        // el/el2 row NN = -1e30 (pad logits -> exp = 0, no masking in agg kernels)
        int j = i - PREP_WV;
        feat_bf[(size_t)NN * 256 + j] = 0;
        if (j < 4) {
            el[NN * 4 + j]  = -1e30f;
            el2[NN * 4 + j] = -1e30f;
        }
    } else if (i < PREP_END) {
        atomicAdd(&deg[dst[i - PREP_SENT]], 1);
    }
}

// ====== 8-wave 128x256 MFMA GEMM for layers 1/2 (N=256, K=256): A read ONCE ======
// Wave w computes 64x64 quadrant (wm=(w>>2)*64, wn=(w&3)*64). Fused logit epilogue:
// wave's 64 output cols = one head (head = w&3).
__global__ __launch_bounds__(512) void gemm256(const unsigned short* __restrict__ A,
                                               const unsigned short* __restrict__ BT,
                                               unsigned short* __restrict__ Cb,
                                               const float* __restrict__ al,
                                               const float* __restrict__ ar,
                                               float* __restrict__ el,
                                               float* __restrict__ er,
                                               int M) {
    const int K = 256;
    __shared__ __align__(16) unsigned short Alds[128 * 32];
    __shared__ __align__(16) unsigned short Blds[256 * 32];
    const int tid = threadIdx.x;
    const int wave = tid >> 6;
    const int lane = tid & 63;
    const int quad = lane >> 4;
    const int ml = lane & 15;
    const int m0 = blockIdx.x * 128;
    const int wm0 = (wave >> 2) * 64;
    const int wn0 = (wave & 3) * 64;

    const unsigned short* Ab = A + (size_t)(m0 + wave * 16 + (lane >> 2)) * K + (lane & 3) * 8;
    const unsigned short* Bb = BT + (size_t)(wave * 16 + (lane >> 2)) * K + (lane & 3) * 8;
    unsigned short* AldsW = Alds + wave * 512;
    unsigned short* BldsW = Blds + wave * 512;

    f32x4 acc[4][4] = {};

    for (int k0 = 0; k0 < K; k0 += 32) {
        load_lds16(Ab + k0, AldsW);
        #pragma unroll
        for (int p = 0; p < 2; ++p)
            load_lds16(Bb + (size_t)(p * 128) * K + k0, BldsW + p * 4096);
        __syncthreads();

        short8 af[4], bf[4];
        #pragma unroll
        for (int i = 0; i < 4; ++i)
            af[i] = *(const short8*)&Alds[(wm0 + i * 16 + ml) * 32 + quad * 8];
        #pragma unroll
        for (int j = 0; j < 4; ++j)
            bf[j] = *(const short8*)&Blds[(wn0 + j * 16 + ml) * 32 + quad * 8];
        #pragma unroll
        for (int i = 0; i < 4; ++i)
            #pragma unroll
            for (int j = 0; j < 4; ++j)
                acc[i][j] = __builtin_amdgcn_mfma_f32_16x16x32_bf16(af[i], bf[j], acc[i][j], 0, 0, 0);
        __syncthreads();
    }

    // C/D layout: col = lane&15, row = quad*4 + reg
    #pragma unroll
    for (int i = 0; i < 4; ++i) {
        #pragma unroll
        for (int reg = 0; reg < 4; ++reg) {
            int m = m0 + wm0 + i * 16 + quad * 4 + reg;
            if (m >= M) continue;
            #pragma unroll
            for (int j = 0; j < 4; ++j) {
                int n = wn0 + j * 16 + ml;
                Cb[(size_t)m * 256 + n] = f2bf(acc[i][j][reg]);
            }
        }
    }

    // ---- fused attention logits: wave's 64 cols = head (wave&3) ----
    {
        int head = wave & 3;
        float alv[4], arv[4];
        #pragma unroll
        for (int j = 0; j < 4; ++j) {
            alv[j] = al[head * 64 + j * 16 + ml];
            arv[j] = ar[head * 64 + j * 16 + ml];
        }
        #pragma unroll
        for (int i = 0; i < 4; ++i) {
            #pragma unroll
            for (int reg = 0; reg < 4; ++reg) {
                float sl = 0.f, sr = 0.f;
                #pragma unroll
                for (int j = 0; j < 4; ++j) {
                    float v = acc[i][j][reg];
                    sl += v * alv[j];
                    sr += v * arv[j];
                }
                #pragma unroll
                for (int off = 1; off < 16; off <<= 1) {
                    sl += __shfl_xor(sl, off);
                    sr += __shfl_xor(sr, off);
                }
                int m = m0 + wm0 + i * 16 + quad * 4 + reg;
                if (ml == 0 && m < M) {
                    el[m * 4 + head] = sl;
                    er[m * 4 + head] = sr;
                }
            }
        }
    }
}

// ================= MFMA GEMM (128x128 tile) — used for the K=1024 output GEMM ======
__global__ __launch_bounds__(256) void gemm_bf16(const unsigned short* __restrict__ A,
                                                 const unsigned short* __restrict__ BT,
                                                 float* __restrict__ Cf,
                                                 int M, int Nout, int K) {
    __shared__ __align__(16) unsigned short Alds[128 * 32];
    __shared__ __align__(16) unsigned short Blds[128 * 32];
    const int tid = threadIdx.x;
    const int wave = tid >> 6;
    const int lane = tid & 63;
    const int quad = lane >> 4;
    const int ml = lane & 15;
    const int m0 = blockIdx.x * 128;
    const int n0 = blockIdx.y * 128;
    const int wm0 = (wave >> 1) * 64;
    const int wn0 = (wave & 1) * 64;

    const unsigned short* Ab = A + (size_t)(m0 + wave * 16 + (lane >> 2)) * K + (lane & 3) * 8;
    const unsigned short* Bb = BT + (size_t)(n0 + wave * 16 + (lane >> 2)) * K + (lane & 3) * 8;
    unsigned short* AldsW = Alds + wave * 512;
    unsigned short* BldsW = Blds + wave * 512;

    f32x4 acc[4][4] = {};

    for (int k0 = 0; k0 < K; k0 += 32) {
        #pragma unroll
        for (int p = 0; p < 2; ++p) {
            load_lds16(Ab + (size_t)(p * 64) * K + k0, AldsW + p * 2048);
            load_lds16(Bb + (size_t)(p * 64) * K + k0, BldsW + p * 2048);
        }
        __syncthreads();

        short8 af[4], bf[4];
        #pragma unroll
        for (int i = 0; i < 4; ++i)
            af[i] = *(const short8*)&Alds[(wm0 + i * 16 + ml) * 32 + quad * 8];
        #pragma unroll
        for (int j = 0; j < 4; ++j)
            bf[j] = *(const short8*)&Blds[(wn0 + j * 16 + ml) * 32 + quad * 8];
        #pragma unroll
        for (int i = 0; i < 4; ++i)
            #pragma unroll
            for (int j = 0; j < 4; ++j)
                acc[i][j] = __builtin_amdgcn_mfma_f32_16x16x32_bf16(af[i], bf[j], acc[i][j], 0, 0, 0);
        __syncthreads();
    }

    // C/D layout: col = lane&15, row = quad*4 + reg
    #pragma unroll
    for (int i = 0; i < 4; ++i) {
        #pragma unroll
        for (int reg = 0; reg < 4; ++reg) {
            int m = m0 + wm0 + i * 16 + quad * 4 + reg;
            if (m >= M) continue;
            #pragma unroll
            for (int j = 0; j < 4; ++j) {
                int n = n0 + wn0 + j * 16 + ml;
                if (n < Nout) Cf[(size_t)m * Nout + n] = acc[i][j][reg];
            }
        }
    }
}

// ======= CSR rowptr via block scan + atomic block-base; fills 4-pad slots inline ====
// pad ssrc -> sentinel row NN (feat zeros, el/el2=-1e30 -> weight exp()=0).
__global__ __launch_bounds__(256) void rowptr_k(const int* __restrict__ deg,
                                                int* __restrict__ rowptr,
                                                int* __restrict__ gtotal,
                                                int* __restrict__ ssrc) {
    __shared__ int sh[256];
    __shared__ int base;
    int i = blockIdx.x * 256 + threadIdx.x;
    int d = (i < NN) ? deg[i] : 0;
    int v = (d + 3) & ~3;
    sh[threadIdx.x] = v;
    __syncthreads();
    for (int off = 1; off < 256; off <<= 1) {
        int t = (threadIdx.x >= off) ? sh[threadIdx.x - off] : 0;
        __syncthreads();
        sh[threadIdx.x] += t;
        __syncthreads();
    }
    if (threadIdx.x == 255) base = atomicAdd(gtotal, sh[255]);
    __syncthreads();
    if (i < NN) {
        int rp = base + sh[threadIdx.x] - v;
        rowptr[i] = rp;
        for (int p = d; p < v; ++p)     // <=3 pad slots
            ssrc[rp + p] = NN << 9;     // sentinel row
    }
}

// scatter: stores BYTE-SCALED src (src*512 = row byte offset in 256-ushort tables)
__global__ __launch_bounds__(256) void scatter_k(const int* __restrict__ src,
                                                 const int* __restrict__ dst,
                                                 const int* __restrict__ rowptr,
                                                 int* __restrict__ cursor,
                                                 int* __restrict__ ssrc) {
    int e = blockIdx.x * blockDim.x + threadIdx.x;
    if (e >= NE) return;
    int d = dst[e];
    int p = atomicAdd(&cursor[d], 1);
    ssrc[rowptr[d] + p] = src[e] << 9;
}

// ===== layers 1/2 aggregation: inline weights, sentinel pads (no masking), 4-unroll =
// el3/er3 (fused layer-3 logit outputs) MUST be disjoint from el/er (read here)!
__global__ __launch_bounds__(256) void agg256(const int* __restrict__ rowptr,
                                              const int* __restrict__ deg,
                                              const int* __restrict__ ssrc,
                                              const float* __restrict__ el,
                                              const float* __restrict__ er,
                                              const unsigned short* __restrict__ feat,
                                              unsigned short* __restrict__ ybf,
                                              const float* __restrict__ wl3,
                                              const float* __restrict__ wr3,
                                              float* __restrict__ el3,
                                              float* __restrict__ er3) {
    int wid = (blockIdx.x * blockDim.x + threadIdx.x) >> 6;
    int lane = threadIdx.x & 63;
    if (wid >= NN) return;
    int n = wid;
    int start = rowptr[n];
    int cnt4 = (deg[n] + 3) & ~3;
    int head = lane >> 4;
    float ern = er[n * 4 + head];
    const char* elb = (const char*)el + head * 4;   // + (src*16) per edge
    const char* fbase = (const char*)feat + lane * 8;
    f32x2 a01 = {0.f, 0.f}, a23 = {0.f, 0.f};
    float ssum = 0.f;
    for (int k = 0; k < cnt4; k += 4) {
        int4 sv = *(const int4*)&ssrc[start + k];   // wave-uniform -> scalar loads
        float e0 = *(const float*)(elb + (sv.x >> 5));
        float e1 = *(const float*)(elb + (sv.y >> 5));
        float e2 = *(const float*)(elb + (sv.z >> 5));
        float e3 = *(const float*)(elb + (sv.w >> 5));
        float v0 = e0 + ern; v0 = fmaxf(v0, 0.2f * v0); float w0 = __expf(v0);
        float v1 = e1 + ern; v1 = fmaxf(v1, 0.2f * v1); float w1 = __expf(v1);
        float v2 = e2 + ern; v2 = fmaxf(v2, 0.2f * v2); float w2 = __expf(v2);
        float v3 = e3 + ern; v3 = fmaxf(v3, 0.2f * v3); float w3 = __expf(v3);
        uint2 u0 = *(const uint2*)(fbase + sv.x);
        uint2 u1 = *(const uint2*)(fbase + sv.y);
        uint2 u2 = *(const uint2*)(fbase + sv.z);
        uint2 u3 = *(const uint2*)(fbase + sv.w);
        ssum += (w0 + w1) + (w2 + w3);
        a01 += w0 * bfpair(u0.x); a23 += w0 * bfpair(u0.y);
        a01 += w1 * bfpair(u1.x); a23 += w1 * bfpair(u1.y);
        a01 += w2 * bfpair(u2.x); a23 += w2 * bfpair(u2.y);
        a01 += w3 * bfpair(u3.x); a23 += w3 * bfpair(u3.y);
    }
    float inv = ssum > 0.f ? 1.0f / ssum : 0.f;
    float r0 = a01.x * inv, r1 = a01.y * inv, r2 = a23.x * inv, r3 = a23.y * inv;
    r0 = r0 > 0.f ? r0 : (__expf(r0) - 1.f);
    r1 = r1 > 0.f ? r1 : (__expf(r1) - 1.f);
    r2 = r2 > 0.f ? r2 : (__expf(r2) - 1.f);
    r3 = r3 > 0.f ? r3 : (__expf(r3) - 1.f);
    ushort4 o;
    o.x = f2bf(r0); o.y = f2bf(r1); o.z = f2bf(r2); o.w = f2bf(r3);
    *(ushort4*)&ybf[(size_t)n * 256 + lane * 4] = o;

    // ---- fused layer-3 logits (layer-2 instance only; writes DISJOINT el3/er3) ----
    if (wl3) {
        float sl[4], sr[4];
        #pragma unroll
        for (int h = 0; h < 4; ++h) {
            float4 a4 = *(const float4*)&wl3[h * 256 + lane * 4];
            float4 b4 = *(const float4*)&wr3[h * 256 + lane * 4];
            sl[h] = r0 * a4.x + r1 * a4.y + r2 * a4.z + r3 * a4.w;
            sr[h] = r0 * b4.x + r1 * b4.y + r2 * b4.z + r3 * b4.w;
        }
        #pragma unroll
        for (int off = 32; off; off >>= 1) {
            #pragma unroll
            for (int h = 0; h < 4; ++h) {
                sl[h] += __shfl_xor(sl[h], off);
                sr[h] += __shfl_xor(sr[h], off);
            }
        }
        if (lane == 0) {
            #pragma unroll
            for (int h = 0; h < 4; ++h) {
                el3[n * 4 + h] = sl[h];
                er3[n * 4 + h] = sr[h];
            }
        }
    }
}

// ===== layer 3: aggregate x2 rows -> xagg[N][4][256] bf16, INLINE edge weights =====
// Weight redundancy removed: per 64-edge chunk, lane e computes edge e's 4 head
// weights ONCE (coalesced ssrc load + scattered el2 float4 + 4 exp, parallel across
// lanes); the iteration loop broadcasts them via wave-uniform __shfl (v_readlane).
// Pads hit sentinel row NN (el2=-1e30 -> w=0). Replaces edgew_k + wcsr entirely.
__global__ __launch_bounds__(256) void agg3(const int* __restrict__ rowptr,
                                            const int* __restrict__ deg,
                                            const int* __restrict__ ssrc,
                                            const float* __restrict__ el,
                                            const float* __restrict__ er,
                                            const unsigned short* __restrict__ x,
                                            unsigned short* __restrict__ xagg) {
    int wid = (blockIdx.x * blockDim.x + threadIdx.x) >> 6;
    int lane = threadIdx.x & 63;
    if (wid >= NN) return;
    int n = wid;
    int start = rowptr[n];
    int cnt4 = (deg[n] + 3) & ~3;
    const char* xbase = (const char*)x + lane * 8;
    float4 ern = *(const float4*)&er[n * 4];
    f32x2 accA[4] = {}, accB[4] = {};
    float ssum[4] = {};
    for (int base = 0; base < cnt4; base += 64) {
        // lane-parallel weight precompute for up to 64 edges of this chunk
        float4 w4 = {0.f, 0.f, 0.f, 0.f};
        int idx = base + lane;
        if (idx < cnt4) {
            int su = ssrc[start + idx];                       // coalesced
            float4 e4 = *(const float4*)((const char*)el + (su >> 5));
            float v0 = e4.x + ern.x; v0 = fmaxf(v0, 0.2f * v0); w4.x = __expf(v0);
            float v1 = e4.y + ern.y; v1 = fmaxf(v1, 0.2f * v1); w4.y = __expf(v1);
            float v2 = e4.z + ern.z; v2 = fmaxf(v2, 0.2f * v2); w4.z = __expf(v2);
            float v3 = e4.w + ern.w; v3 = fmaxf(v3, 0.2f * v3); w4.w = __expf(v3);
        }
        int rem = cnt4 - base;
        int kend = rem > 64 ? 64 : rem;
        for (int k = 0; k < kend; k += 4) {
            int4 sv = *(const int4*)&ssrc[start + base + k];
            // broadcast the 4 edges' head-weight quads (uniform src lane -> readlane)
            float4 wE0, wE1, wE2, wE3;
            wE0.x = __shfl(w4.x, k);     wE0.y = __shfl(w4.y, k);
            wE0.z = __shfl(w4.z, k);     wE0.w = __shfl(w4.w, k);
            wE1.x = __shfl(w4.x, k + 1); wE1.y = __shfl(w4.y, k + 1);
            wE1.z = __shfl(w4.z, k + 1); wE1.w = __shfl(w4.w, k + 1);
            wE2.x = __shfl(w4.x, k + 2); wE2.y = __shfl(w4.y, k + 2);
            wE2.z = __shfl(w4.z, k + 2); wE2.w = __shfl(w4.w, k + 2);
            wE3.x = __shfl(w4.x, k + 3); wE3.y = __shfl(w4.y, k + 3);
            wE3.z = __shfl(w4.z, k + 3); wE3.w = __shfl(w4.w, k + 3);
            uint2 u0 = *(const uint2*)(xbase + sv.x);
            uint2 u1 = *(const uint2*)(xbase + sv.y);
            uint2 u2 = *(const uint2*)(xbase + sv.z);
            uint2 u3 = *(const uint2*)(xbase + sv.w);
            ssum[0] += (wE0.x + wE1.x) + (wE2.x + wE3.x);
            ssum[1] += (wE0.y + wE1.y) + (wE2.y + wE3.y);
            ssum[2] += (wE0.z + wE1.z) + (wE2.z + wE3.z);
            ssum[3] += (wE0.w + wE1.w) + (wE2.w + wE3.w);
            f32x2 fa = bfpair(u0.x), fA = bfpair(u0.y);
            f32x2 fb = bfpair(u1.x), fB = bfpair(u1.y);
            f32x2 fc = bfpair(u2.x), fC = bfpair(u2.y);
            f32x2 fd = bfpair(u3.x), fD = bfpair(u3.y);
            accA[0] += wE0.x * fa + wE1.x * fb + wE2.x * fc + wE3.x * fd;
            accB[0] += wE0.x * fA + wE1.x * fB + wE2.x * fC + wE3.x * fD;
            accA[1] += wE0.y * fa + wE1.y * fb + wE2.y * fc + wE3.y * fd;
            accB[1] += wE0.y * fA + wE1.y * fB + wE2.y * fC + wE3.y * fD;
            accA[2] += wE0.z * fa + wE1.z * fb + wE2.z * fc + wE3.z * fd;
            accB[2] += wE0.z * fA + wE1.z * fB + wE2.z * fC + wE3.z * fD;
            accA[3] += wE0.w * fa + wE1.w * fb + wE2.w * fc + wE3.w * fd;
            accB[3] += wE0.w * fA + wE1.w * fB + wE2.w * fC + wE3.w * fD;
        }
    }
    #pragma unroll
    for (int h = 0; h < 4; ++h) {
        float inv = ssum[h] > 0.f ? 1.f / ssum[h] : 0.f;
        ushort4 o;
        o.x = f2bf(accA[h].x * inv); o.y = f2bf(accA[h].y * inv);
        o.z = f2bf(accB[h].x * inv); o.w = f2bf(accB[h].y * inv);
        *(ushort4*)&xagg[(size_t)n * 1024 + h * 256 + lane * 4] = o;
    }
}

extern "C" void kernel_launch(void* const* d_in, const int* in_sizes, int n_in,
                              void* d_out, int out_size, void* d_ws, size_t ws_size,
                              hipStream_t stream) {
    const float* h   = (const float*)d_in[0];
    const int*   src = (const int*)d_in[1];
    const int*   dst = (const int*)d_in[2];
    const float* W1  = (const float*)d_in[3];
    const float* al1 = (const float*)d_in[4];
    const float* ar1 = (const float*)d_in[5];
    const float* W2  = (const float*)d_in[6];
    const float* al2 = (const float*)d_in[7];
    const float* ar2 = (const float*)d_in[8];
    const float* W3  = (const float*)d_in[9];
    const float* al3 = (const float*)d_in[10];
    const float* ar3 = (const float*)d_in[11];
    float* out = (float*)d_out;

    float* ws = (float*)d_ws;
    unsigned short* x_bf    = (unsigned short*)ws;
    unsigned short* h_bf    = (unsigned short*)(ws + 6400000);
    unsigned short* feat_bf = (unsigned short*)(ws + 12800000);  // +1 sentinel row
    unsigned short* xagg    = (unsigned short*)(ws + 6400000);   // overlays h_bf+feat_bf (dead by L3)
    float* el  = ws + 32000000;                  // 50001 rows x 4 (row NN = sentinel)
    float* er  = ws + 32200064;
    float* wl3 = ws + 32400064;
    float* wr3 = ws + 32401088;
    unsigned short* BT1   = (unsigned short*)(ws + 32402112);
    unsigned short* BT2   = (unsigned short*)(ws + 32434880);
    unsigned short* BTcat = (unsigned short*)(ws + 32467648);
    int* ibase  = (int*)(ws + 32533184);
    int* deg      = ibase;                       // 50,000
    int* cursor   = ibase + 50000;               // 50,000 (adjacent: one memset)
    int* gtotal   = ibase + 100000;              // 1 (same memset range)
    int* rowptr   = ibase + 100256;              // 50,000
    int* ssrc     = ibase + 150256;              // 600,000 (byte-scaled src)
    float* el2 = ws + 33283440;                  // 50001 rows x 4 (row NN = sentinel)
    float* er2 = ws + 33483504;                  // 200,000

    const int NB = (NN + 255) / 256;

    // ---- single memset: deg + cursor + gtotal (pads handled inside rowptr_k) ----
    hipMemsetAsync(deg, 0, (2 * NN + 1) * sizeof(int), stream);

    // ---- fused prep: casts + weight prep + sentinels + dst histogram ----
    prep_k<<<(PREP_END + 255) / 256, 256, 0, stream>>>(h, W1, W2, W3, al3, ar3, dst,
                                                       h_bf, BT1, BT2, BTcat, wl3, wr3,
                                                       feat_bf, el, el2, deg);

    // ---- CSR build: one scan kernel (atomic block base + inline pad-fill) ----
    rowptr_k<<<NB, 256, 0, stream>>>(deg, rowptr, gtotal, ssrc);
    scatter_k<<<(NE + 255) / 256, 256, 0, stream>>>(src, dst, rowptr, cursor, ssrc);

    const int GB = (NN + 127) / 128;             // 391 blocks, full 256-col tile
    const int WAVE_BLOCKS = (NN * 64 + 255) / 256;   // one wave per node

    // ---- layer 1 (agg computes edge weights inline from el/er; sentinel pads) ----
    gemm256<<<GB, 512, 0, stream>>>(h_bf, BT1, feat_bf, al1, ar1, el, er, NN);
    agg256<<<WAVE_BLOCKS, 256, 0, stream>>>(rowptr, deg, ssrc, el, er, feat_bf, x_bf,
                                            nullptr, nullptr, nullptr, nullptr);

    // ---- layer 2 (fused layer-3 logit epilogue -> el2/er2, disjoint) ----
    gemm256<<<GB, 512, 0, stream>>>(x_bf, BT2, feat_bf, al2, ar2, el, er, NN);
    agg256<<<WAVE_BLOCKS, 256, 0, stream>>>(rowptr, deg, ssrc, el, er, feat_bf, x_bf,
                                            wl3, wr3, el2, er2);

    // ---- layer 3 (inline weights via lane-parallel precompute + shfl broadcast) ----
    agg3<<<WAVE_BLOCKS, 256, 0, stream>>>(rowptr, deg, ssrc, el2, er2, x_bf, xagg);
    gemm_bf16<<<dim3(GB, 1), 256, 0, stream>>>(xagg, BTcat, out, NN, NC, 1024);
}